// Round 1
// baseline (697.427 us; speedup 1.0000x reference)
//
#include <hip/hip_runtime.h>
#include <math.h>

#define EPSF 1e-7f

__device__ __forceinline__ float iou_pair(const float4 a, const float4 b) {
    float iw = fminf(a.z, b.z) - fmaxf(a.x, b.x); iw = iw > 0.f ? iw : 0.f;
    float ih = fminf(a.w, b.w) - fmaxf(a.y, b.y); ih = ih > 0.f ? ih : 0.f;
    float inter = iw * ih;
    float aa = (a.z - a.x) * (a.w - a.y);
    float ab = (b.z - b.x) * (b.w - b.y);
    return inter / (aa + ab - inter + EPSF);
}

__global__ __launch_bounds__(256) void k_init(double* acc, int n) {
    int i = blockIdx.x * blockDim.x + threadIdx.x;
    if (i < n) acc[i] = 0.0;
}

// Per-anchor: max_iou over valid GTs (invalid => -1 mask), argmax (first index wins),
// matching jnp.where(valid, iou, -1).max(-1)/argmax(-1).
__global__ __launch_bounds__(256) void k_anchor(const float4* __restrict__ bbox_true,
                                                const float4* __restrict__ anchors,
                                                float* __restrict__ max_iou,
                                                int* __restrict__ ti,
                                                unsigned char* __restrict__ pos_ovr,
                                                int P, int A) {
    int n = blockIdx.y;
    int a = blockIdx.x * blockDim.x + threadIdx.x;
    extern __shared__ char smem[];
    float4* sraw = (float4*)smem;          // P raw boxes
    float4* scb  = sraw + P;               // compacted valid boxes (order preserved)
    int*    sidx = (int*)(scb + P);        // original p index of compacted entries
    __shared__ int sV;
    for (int p = threadIdx.x; p < P; p += blockDim.x)
        sraw[p] = bbox_true[(size_t)n * P + p];
    __syncthreads();
    if (threadIdx.x == 0) {
        int v = 0;
        for (int p = 0; p < P; p++) {
            float4 b = sraw[p];
            if (b.x > 0.f || b.y > 0.f || b.z > 0.f || b.w > 0.f) {
                scb[v] = b; sidx[v] = p; v++;
            }
        }
        sV = v;
    }
    __syncthreads();
    if (a >= A) return;
    float4 an = anchors[a];
    int V = sV;
    float best = -2.f; int bi = 0;
    for (int k = 0; k < V; k++) {
        float iou = iou_pair(an, scb[k]);
        if (iou > best) { best = iou; bi = sidx[k]; }  // strict > keeps first index
    }
    if (V == 0) best = -1.f;   // all columns masked to -1; argmax -> 0
    size_t o = (size_t)n * A + a;
    max_iou[o] = best;
    ti[o] = bi;
    pos_ovr[o] = 0;
}

// Per-GT: max/argmax over all anchors (first anchor index wins on ties).
// Invalid GT rows: gt_max=-1, gt_best=0 (argmax of all -1 column is index 0).
__global__ __launch_bounds__(256) void k_gt(const float4* __restrict__ bbox_true,
                                            const float4* __restrict__ anchors,
                                            float* __restrict__ gt_max,
                                            int* __restrict__ gt_best,
                                            int P, int A) {
    int p = blockIdx.x, n = blockIdx.y;
    float4 b = bbox_true[(size_t)n * P + p];
    bool valid = (b.x > 0.f || b.y > 0.f || b.z > 0.f || b.w > 0.f);
    if (!valid) {  // uniform across block: safe early return
        if (threadIdx.x == 0) { gt_max[n * P + p] = -1.f; gt_best[n * P + p] = 0; }
        return;
    }
    float best = -2.f; int bi = 0x7fffffff;
    for (int a = threadIdx.x; a < A; a += blockDim.x) {
        float iou = iou_pair(anchors[a], b);
        if (iou > best) { best = iou; bi = a; }
    }
    __shared__ float sv[256];
    __shared__ int   si[256];
    int tid = threadIdx.x;
    sv[tid] = best; si[tid] = bi;
    __syncthreads();
    for (int s = 128; s > 0; s >>= 1) {
        if (tid < s) {
            if (sv[tid + s] > sv[tid] ||
                (sv[tid + s] == sv[tid] && si[tid + s] < si[tid])) {
                sv[tid] = sv[tid + s]; si[tid] = si[tid + s];
            }
        }
        __syncthreads();
    }
    if (tid == 0) { gt_max[n * P + p] = sv[0]; gt_best[n * P + p] = si[0]; }
}

// Emulate JAX scatter semantics exactly: gather original ti[gt_best[p]] for ALL p
// first, then apply updates in p-order (last-wins). Non-lowq rows write back the
// ORIGINAL gathered value (can revert an earlier lowq write). pos scatter is .max
// so only lowq rows set pos_ovr.
__global__ void k_scatter(const float* __restrict__ gt_max,
                          const int* __restrict__ gt_best,
                          int* __restrict__ ti,
                          unsigned char* __restrict__ pos_ovr,
                          int* __restrict__ orig,
                          int N, int P, int A) {
    int n = blockIdx.x * blockDim.x + threadIdx.x;
    if (n >= N) return;
    for (int p = 0; p < P; p++)
        orig[n * P + p] = ti[(size_t)n * A + gt_best[n * P + p]];
    for (int p = 0; p < P; p++) {
        int idx = gt_best[n * P + p];
        if (gt_max[n * P + p] > 0.f) {   // lowq = valid & gt_max>0 (invalid forced to -1)
            ti[(size_t)n * A + idx] = p;
            pos_ovr[(size_t)n * A + idx] = 1;
        } else {
            ti[(size_t)n * A + idx] = orig[n * P + p];
        }
    }
}

__global__ __launch_bounds__(256) void k_loss(const float* __restrict__ conf,
                                              const float* __restrict__ logit,
                                              const float4* __restrict__ bbox_pred,
                                              const float* __restrict__ y_true,
                                              const float4* __restrict__ bbox_true,
                                              const float* __restrict__ max_iou,
                                              const int* __restrict__ ti,
                                              const unsigned char* __restrict__ pos_ovr,
                                              double* __restrict__ acc,
                                              int P, int A, int C) {
    int n = blockIdx.y;
    int a = blockIdx.x * blockDim.x + threadIdx.x;
    double sc = 0.0, cl = 0.0, bb = 0.0, pc = 0.0;
    if (a < A) {
        size_t o = (size_t)n * A + a;
        float mi = max_iou[o];
        bool pos = (mi >= 0.5f) || (pos_ovr[o] != 0);
        bool neg = (mi < 0.4f) && !pos;
        float p = conf[o];
        p = fminf(fmaxf(p, EPSF), 1.f - EPSF);
        if (pos || neg) sc = (double)(pos ? -logf(p) : -logf(1.f - p));
        if (pos) {
            pc = 1.0;
            int t = ti[o];
            const float* yt = y_true + ((size_t)n * P + t) * C;
            const float* lg = logit + o * C;
            float s = 0.f;
            for (int c = 0; c < C; c++) {
                float tl = yt[c];
                float q = fminf(fmaxf(lg[c], EPSF), 1.f - EPSF);
                float pt = tl * q + (1.f - tl) * (1.f - q);
                float at = tl * 0.25f + (1.f - tl) * 0.75f;
                float om = 1.f - pt;
                s += -at * om * om * logf(pt);
            }
            cl = (double)s;
            // CIoU(bt = bbox_true[n, t], bp = bbox_pred[n, a])
            float4 bt = bbox_true[(size_t)n * P + t];
            float4 bp = bbox_pred[o];
            float ix1 = fmaxf(bt.x, bp.x), iy1 = fmaxf(bt.y, bp.y);
            float ix2 = fminf(bt.z, bp.z), iy2 = fminf(bt.w, bp.w);
            float iw = ix2 - ix1; iw = iw > 0.f ? iw : 0.f;
            float ih = iy2 - iy1; ih = ih > 0.f ? ih : 0.f;
            float inter = iw * ih;
            float wt = bt.z - bt.x, ht = bt.w - bt.y;
            float wp = bp.z - bp.x, hp = bp.w - bp.y;
            float uni = wt * ht + wp * hp - inter + EPSF;
            float iou = inter / uni;
            float cw = fmaxf(bt.z, bp.z) - fminf(bt.x, bp.x);
            float ch = fmaxf(bt.w, bp.w) - fminf(bt.y, bp.y);
            float c2 = cw * cw + ch * ch + EPSF;
            float dx = bt.x + bt.z - bp.x - bp.z;
            float dy = bt.y + bt.w - bp.y - bp.w;
            float rho2 = (dx * dx + dy * dy) * 0.25f;
            float dd = atanf(wt / (ht + EPSF)) - atanf(wp / (hp + EPSF));
            float v = 0.40528473456935109f * dd * dd;   // 4/pi^2
            float al = v / (1.f - iou + v + EPSF);
            bb = (double)(1.f - iou + rho2 / c2 + al * v);
        }
    }
    // wave-64 reduce, then fp64 atomic per wave
    for (int off = 32; off > 0; off >>= 1) {
        sc += __shfl_down(sc, off, 64);
        cl += __shfl_down(cl, off, 64);
        bb += __shfl_down(bb, off, 64);
        pc += __shfl_down(pc, off, 64);
    }
    if ((threadIdx.x & 63) == 0) {
        if (sc != 0.0) atomicAdd(&acc[0], sc);
        if (cl != 0.0) atomicAdd(&acc[1], cl);
        if (bb != 0.0) atomicAdd(&acc[2], bb);
        if (pc != 0.0) atomicAdd(&acc[3 + n], pc);
    }
}

__global__ void k_final(const double* __restrict__ acc, float* __restrict__ out, int N) {
    if (blockIdx.x == 0 && threadIdx.x == 0) {
        double avg = 0.0;
        for (int n = 0; n < N; n++) {
            double c = acc[3 + n];
            avg += c > 1.0 ? c : 1.0;
        }
        double r[3] = {acc[0] / avg, acc[1] / avg, acc[2] / avg};
        for (int i = 0; i < 3; i++) {
            double x = r[i];
            if (isnan(x) || isinf(x)) x = 0.0;
            out[i] = (float)x;
        }
    }
}

extern "C" void kernel_launch(void* const* d_in, const int* in_sizes, int n_in,
                              void* d_out, int out_size, void* d_ws, size_t ws_size,
                              hipStream_t stream) {
    const float* y_true    = (const float*)d_in[0];
    const float* bbox_true = (const float*)d_in[1];
    const float* conf      = (const float*)d_in[2];
    const float* logit     = (const float*)d_in[3];
    const float* bboxp     = (const float*)d_in[4];
    const float* anchors   = (const float*)d_in[5];

    int A = in_sizes[5] / 4;            // anchors: (A,4)
    int N = in_sizes[2] / A;            // conf:    (N,A,1)
    int P = in_sizes[1] / (4 * N);      // bbox_true: (N,P,4)
    int C = in_sizes[0] / (N * P);      // y_true: (N,P,C)

    char* w = (char*)d_ws;
    auto alloc = [&](size_t bytes) -> void* {
        void* r = (void*)w;
        w += (bytes + 15) & ~(size_t)15;
        return r;
    };
    double* acc          = (double*)alloc(sizeof(double) * (size_t)(3 + N));
    float* max_iou       = (float*)alloc(sizeof(float) * (size_t)N * A);
    int* ti              = (int*)alloc(sizeof(int) * (size_t)N * A);
    float* gt_max        = (float*)alloc(sizeof(float) * (size_t)N * P);
    int* gt_best         = (int*)alloc(sizeof(int) * (size_t)N * P);
    int* orig            = (int*)alloc(sizeof(int) * (size_t)N * P);
    unsigned char* p_ovr = (unsigned char*)alloc((size_t)N * A);

    k_init<<<1, 256, 0, stream>>>(acc, 3 + N);

    dim3 gA((A + 255) / 256, N);
    size_t shA = (size_t)P * (16 + 16 + 4);
    k_anchor<<<gA, 256, shA, stream>>>((const float4*)bbox_true, (const float4*)anchors,
                                       max_iou, ti, p_ovr, P, A);

    dim3 gG(P, N);
    k_gt<<<gG, 256, 0, stream>>>((const float4*)bbox_true, (const float4*)anchors,
                                 gt_max, gt_best, P, A);

    k_scatter<<<(N + 63) / 64, 64, 0, stream>>>(gt_max, gt_best, ti, p_ovr, orig, N, P, A);

    k_loss<<<gA, 256, 0, stream>>>(conf, logit, (const float4*)bboxp, y_true,
                                   (const float4*)bbox_true, max_iou, ti, p_ovr,
                                   acc, P, A, C);

    k_final<<<1, 64, 0, stream>>>(acc, (float*)d_out, N);
}

// Round 2
// 445.526 us; speedup vs baseline: 1.5654x; 1.5654x over previous
//
#include <hip/hip_runtime.h>
#include <math.h>

#define EPSF 1e-7f

__device__ __forceinline__ float iou_pair(const float4 a, const float4 b) {
    float iw = fminf(a.z, b.z) - fmaxf(a.x, b.x); iw = iw > 0.f ? iw : 0.f;
    float ih = fminf(a.w, b.w) - fmaxf(a.y, b.y); ih = ih > 0.f ? ih : 0.f;
    float inter = iw * ih;
    float aa = (a.z - a.x) * (a.w - a.y);
    float ab = (b.z - b.x) * (b.w - b.y);
    return inter / (aa + ab - inter + EPSF);
}

// Per-GT: max/argmax over all anchors (first anchor index wins on ties).
// Invalid GT rows: gt_max=-1, gt_best=0.
__global__ __launch_bounds__(256) void k_gt(const float4* __restrict__ bbox_true,
                                            const float4* __restrict__ anchors,
                                            float* __restrict__ gt_max,
                                            int* __restrict__ gt_best,
                                            int P, int A) {
    int p = blockIdx.x, n = blockIdx.y;
    float4 b = bbox_true[(size_t)n * P + p];
    bool valid = (b.x > 0.f || b.y > 0.f || b.z > 0.f || b.w > 0.f);
    if (!valid) {  // uniform across block: safe early return
        if (threadIdx.x == 0) { gt_max[n * P + p] = -1.f; gt_best[n * P + p] = 0; }
        return;
    }
    float best = -2.f; int bi = 0x7fffffff;
    for (int a = threadIdx.x; a < A; a += blockDim.x) {
        float iou = iou_pair(anchors[a], b);
        if (iou > best) { best = iou; bi = a; }
    }
    __shared__ float sv[256];
    __shared__ int   si[256];
    int tid = threadIdx.x;
    sv[tid] = best; si[tid] = bi;
    __syncthreads();
    for (int s = 128; s > 0; s >>= 1) {
        if (tid < s) {
            if (sv[tid + s] > sv[tid] ||
                (sv[tid + s] == sv[tid] && si[tid + s] < si[tid])) {
                sv[tid] = sv[tid + s]; si[tid] = si[tid + s];
            }
        }
        __syncthreads();
    }
    if (tid == 0) { gt_max[n * P + p] = sv[0]; gt_best[n * P + p] = si[0]; }
}

// Sparse override map with exact JAX scatter semantics (serial in p, last-wins):
//   ovr[o] == -1 : untouched (pos=0, ti = anchor's own argmax)
//   ovr[o] == -2 : pos=1, ti = anchor's own argmax (lowq later reverted)
//   ovr[o] >=  0 : pos=1, ti = ovr[o]
// lowq rows write p; non-lowq rows "revert" ti to original (only matters if an
// entry already exists -> becomes -2; pos flag is sticky per .at[].max semantics).
__global__ void k_scatter(const float* __restrict__ gt_max,
                          const int* __restrict__ gt_best,
                          int* __restrict__ ovr,
                          int N, int P, int A) {
    int n = blockIdx.x * blockDim.x + threadIdx.x;
    if (n >= N) return;
    for (int p = 0; p < P; p++) {
        int idx = gt_best[n * P + p];
        size_t o = (size_t)n * A + idx;
        if (gt_max[n * P + p] > 0.f) {
            ovr[o] = p;
        } else {
            int cur = ovr[o];
            if (cur != -1) ovr[o] = -2;
        }
    }
}

// Fused: per-anchor assignment (max/argmax over valid GTs staged in LDS) +
// override lookup + all three losses + block reduction into partials.
__global__ __launch_bounds__(256) void k_fused(const float4* __restrict__ bbox_true,
                                               const float4* __restrict__ anchors,
                                               const float* __restrict__ conf,
                                               const float* __restrict__ logit,
                                               const float4* __restrict__ bbox_pred,
                                               const float* __restrict__ y_true,
                                               const int* __restrict__ ovr,
                                               double* __restrict__ partial,
                                               int P, int A, int C, int BX) {
    int tid = threadIdx.x;
    int n = blockIdx.y;
    int a = blockIdx.x * blockDim.x + tid;

    __shared__ float4 scb[256];   // compacted valid GT boxes (order preserved)
    __shared__ int    sidx[256];  // original p index
    __shared__ int    wcnt[4];

    // ballot-compaction of valid GTs (P <= 256)
    float4 b = make_float4(0.f, 0.f, 0.f, 0.f);
    bool v = false;
    if (tid < P) {
        b = bbox_true[(size_t)n * P + tid];
        v = (b.x > 0.f || b.y > 0.f || b.z > 0.f || b.w > 0.f);
    }
    unsigned long long m = __ballot(v);
    int lane = tid & 63, wv = tid >> 6;
    if (lane == 0) wcnt[wv] = __popcll(m);
    int posn = __popcll(m & ((1ull << lane) - 1ull));
    __syncthreads();
    int base = 0;
    for (int w = 0; w < wv; w++) base += wcnt[w];
    int V = wcnt[0] + wcnt[1] + wcnt[2] + wcnt[3];
    if (v) { scb[base + posn] = b; sidx[base + posn] = tid; }
    __syncthreads();

    double sc = 0.0, cl = 0.0, bb = 0.0, pc = 0.0;
    if (a < A) {
        float4 an = anchors[a];
        float best = -2.f; int bi = 0;
        for (int k = 0; k < V; k++) {
            float iou = iou_pair(an, scb[k]);
            if (iou > best) { best = iou; bi = sidx[k]; }  // strict > : first index wins
        }
        if (V == 0) best = -1.f;
        size_t o = (size_t)n * A + a;
        int ov = ovr[o];
        bool pos = (best >= 0.5f) || (ov != -1);
        bool neg = (best < 0.4f) && !pos;
        int t = (ov >= 0) ? ov : bi;

        float p = conf[o];
        p = fminf(fmaxf(p, EPSF), 1.f - EPSF);
        if (pos || neg) sc = (double)(pos ? -logf(p) : -logf(1.f - p));
        if (pos) {
            pc = 1.0;
            const float* yt = y_true + ((size_t)n * P + t) * C;
            const float* lg = logit + o * C;
            float s = 0.f;
            for (int c = 0; c < C; c++) {
                float tl = yt[c];
                float q = fminf(fmaxf(lg[c], EPSF), 1.f - EPSF);
                float pt = tl * q + (1.f - tl) * (1.f - q);
                float at = tl * 0.25f + (1.f - tl) * 0.75f;
                float om = 1.f - pt;
                s += -at * om * om * logf(pt);
            }
            cl = (double)s;
            float4 bt = bbox_true[(size_t)n * P + t];
            float4 bp = bbox_pred[o];
            float ix1 = fmaxf(bt.x, bp.x), iy1 = fmaxf(bt.y, bp.y);
            float ix2 = fminf(bt.z, bp.z), iy2 = fminf(bt.w, bp.w);
            float iw = ix2 - ix1; iw = iw > 0.f ? iw : 0.f;
            float ih = iy2 - iy1; ih = ih > 0.f ? ih : 0.f;
            float inter = iw * ih;
            float wt = bt.z - bt.x, ht = bt.w - bt.y;
            float wp = bp.z - bp.x, hp = bp.w - bp.y;
            float uni = wt * ht + wp * hp - inter + EPSF;
            float iou = inter / uni;
            float cw = fmaxf(bt.z, bp.z) - fminf(bt.x, bp.x);
            float ch = fmaxf(bt.w, bp.w) - fminf(bt.y, bp.y);
            float c2 = cw * cw + ch * ch + EPSF;
            float dx = bt.x + bt.z - bp.x - bp.z;
            float dy = bt.y + bt.w - bp.y - bp.w;
            float rho2 = (dx * dx + dy * dy) * 0.25f;
            float dd = atanf(wt / (ht + EPSF)) - atanf(wp / (hp + EPSF));
            float vv = 0.40528473456935109f * dd * dd;   // 4/pi^2
            float al = vv / (1.f - iou + vv + EPSF);
            bb = (double)(1.f - iou + rho2 / c2 + al * vv);
        }
    }

    // block reduction: wave shuffle, then cross-wave via LDS, zero atomics
    for (int off = 32; off > 0; off >>= 1) {
        sc += __shfl_down(sc, off, 64);
        cl += __shfl_down(cl, off, 64);
        bb += __shfl_down(bb, off, 64);
        pc += __shfl_down(pc, off, 64);
    }
    __shared__ double sred[4][4];
    if (lane == 0) { sred[wv][0] = sc; sred[wv][1] = cl; sred[wv][2] = bb; sred[wv][3] = pc; }
    __syncthreads();
    if (tid == 0) {
        double r0 = 0, r1 = 0, r2 = 0, r3 = 0;
        for (int w = 0; w < 4; w++) {
            r0 += sred[w][0]; r1 += sred[w][1]; r2 += sred[w][2]; r3 += sred[w][3];
        }
        double* row = partial + ((size_t)n * BX + blockIdx.x) * 4;
        row[0] = r0; row[1] = r1; row[2] = r2; row[3] = r3;
    }
}

__global__ __launch_bounds__(256) void k_final(const double* __restrict__ partial,
                                               float* __restrict__ out, int N, int BX) {
    const int FT = 256;
    int tid = threadIdx.x;
    __shared__ double sh[FT];
    __shared__ double res[3];
    __shared__ double shn[64];

    double s0 = 0, s1 = 0, s2 = 0;
    int total = N * BX;
    for (int i = tid; i < total; i += FT) {
        const double* r = partial + (size_t)i * 4;
        s0 += r[0]; s1 += r[1]; s2 += r[2];
    }
    // three LDS tree-reductions
    double vals[3] = {s0, s1, s2};
    for (int k = 0; k < 3; k++) {
        sh[tid] = vals[k];
        __syncthreads();
        for (int s = 128; s > 0; s >>= 1) {
            if (tid < s) sh[tid] += sh[tid + s];
            __syncthreads();
        }
        if (tid == 0) res[k] = sh[0];
        __syncthreads();
    }
    // per-image positive counts, clamped at 1, then summed
    int chunks = FT / N;                 // N=32 -> 8 threads per image
    double pcs = 0;
    int n = tid / chunks, c = tid % chunks;
    if (n < N) {
        int per = (BX + chunks - 1) / chunks;
        int j0 = c * per, j1 = (j0 + per < BX) ? j0 + per : BX;
        for (int j = j0; j < j1; j++) pcs += partial[((size_t)n * BX + j) * 4 + 3];
    }
    sh[tid] = pcs;
    __syncthreads();
    if (tid < N) {
        double s = 0;
        for (int c2 = 0; c2 < chunks; c2++) s += sh[tid * chunks + c2];
        shn[tid] = s > 1.0 ? s : 1.0;
    }
    __syncthreads();
    if (tid == 0) {
        double avg = 0;
        for (int i = 0; i < N; i++) avg += shn[i];
        for (int k = 0; k < 3; k++) {
            double x = res[k] / avg;
            if (isnan(x) || isinf(x)) x = 0.0;
            out[k] = (float)x;
        }
    }
}

extern "C" void kernel_launch(void* const* d_in, const int* in_sizes, int n_in,
                              void* d_out, int out_size, void* d_ws, size_t ws_size,
                              hipStream_t stream) {
    const float* y_true    = (const float*)d_in[0];
    const float* bbox_true = (const float*)d_in[1];
    const float* conf      = (const float*)d_in[2];
    const float* logit     = (const float*)d_in[3];
    const float* bboxp     = (const float*)d_in[4];
    const float* anchors   = (const float*)d_in[5];

    int A = in_sizes[5] / 4;            // anchors: (A,4)
    int N = in_sizes[2] / A;            // conf:    (N,A,1)
    int P = in_sizes[1] / (4 * N);      // bbox_true: (N,P,4)
    int C = in_sizes[0] / (N * P);      // y_true: (N,P,C)

    int BX = (A + 255) / 256;

    char* w = (char*)d_ws;
    auto alloc = [&](size_t bytes) -> void* {
        void* r = (void*)w;
        w += (bytes + 15) & ~(size_t)15;
        return r;
    };
    int*    ovr     = (int*)alloc(sizeof(int) * (size_t)N * A);
    float*  gt_max  = (float*)alloc(sizeof(float) * (size_t)N * P);
    int*    gt_best = (int*)alloc(sizeof(int) * (size_t)N * P);
    double* partial = (double*)alloc(sizeof(double) * (size_t)N * BX * 4);

    hipMemsetAsync(ovr, 0xFF, sizeof(int) * (size_t)N * A, stream);  // all -1

    dim3 gG(P, N);
    k_gt<<<gG, 256, 0, stream>>>((const float4*)bbox_true, (const float4*)anchors,
                                 gt_max, gt_best, P, A);

    k_scatter<<<(N + 63) / 64, 64, 0, stream>>>(gt_max, gt_best, ovr, N, P, A);

    dim3 gA(BX, N);
    k_fused<<<gA, 256, 0, stream>>>((const float4*)bbox_true, (const float4*)anchors,
                                    conf, logit, (const float4*)bboxp, y_true,
                                    ovr, partial, P, A, C, BX);

    k_final<<<1, 256, 0, stream>>>(partial, (float*)d_out, N, BX);
}